// Round 4
// baseline (435.344 us; speedup 1.0000x reference)
//
#include <hip/hip_runtime.h>
#include <hip/hip_bf16.h>
#include <math.h>

#define B_    32
#define NIN_  2312
#define NHID_ 512
#define NOUT_ 10
#define T_    350
#define KLEN  77      // truncated SRM alpha kernel length (taps 0..76)
#define MW    40      // u64 words per (b,t) input mask row (37 used, padded)
#define NIB   37      // ceil(NIN/64)
#define NTC   22      // ceil(T/16)
#define MAXA2 320     // max active inputs per (b,t); Binom(2312,0.03) max ~110

// ---------------- W1 transpose: W1[o][i] -> W1T[i][o] ----------------
__global__ __launch_bounds__(256) void w1t_k(const float* __restrict__ W,
                                             float* __restrict__ WT) {
  __shared__ float tile[32][33];
  int i0 = blockIdx.x * 32, o0 = blockIdx.y * 32;
  int tx = threadIdx.x, tyb = threadIdx.y;
#pragma unroll
  for (int s = 0; s < 4; ++s) {
    int ty = tyb + s * 8;
    int o = o0 + ty, i = i0 + tx;
    if (i < NIN_) tile[ty][tx] = W[(size_t)o * NIN_ + i];
  }
  __syncthreads();
#pragma unroll
  for (int s = 0; s < 4; ++s) {
    int ty = tyb + s * 8;
    int i = i0 + ty, o = o0 + tx;
    if (i < NIN_) WT[(size_t)i * NHID_ + o] = tile[tx][ty];
  }
}

// ------------- input bitmask via ballot-transpose: NO atomics, no memset -------------
// wave owns (b, 64-i block, 16-t chunk). Lane = i. Each lane reads 16 consecutive
// t of its own row (64B granule, fully used); 16 ballots produce mask words that
// this wave exclusively owns -> plain stores.
__global__ __launch_bounds__(256) void inmask_k(const float* __restrict__ X,
                                                unsigned long long* __restrict__ msk) {
  int w = blockIdx.x * 4 + (threadIdx.x >> 6);
  int lane = threadIdx.x & 63;
  if (w >= B_ * NIB * NTC) return;
  int b = w / (NIB * NTC);
  int rem = w - b * (NIB * NTC);
  int iblk = rem / NTC, tc = rem - iblk * NTC;
  int i = iblk * 64 + lane;
  int t0 = tc * 16;
  int nk = (t0 + 16 <= T_) ? 16 : (T_ - t0);      // wave-uniform (depends on tc only)
  bool valid = (i < NIN_);
  const float2* rp = (const float2*)(X + ((size_t)b * NIN_ + (valid ? i : 0)) * T_ + t0);
  float2 v[8];
#pragma unroll
  for (int q = 0; q < 8; ++q) v[q] = make_float2(0.f, 0.f);
  if (valid) {
    int nw = nk >> 1;
    for (int q = 0; q < nw; ++q) v[q] = rp[q];
  }
  unsigned long long* mrow = msk + ((size_t)b * T_ + t0) * MW + iblk;
#pragma unroll
  for (int k = 0; k < 16; ++k) {
    if (k >= nk) break;                            // wave-uniform exit
    float xv = (k & 1) ? v[k >> 1].y : v[k >> 1].x;
    unsigned long long bw = __ballot(xv != 0.0f);
    if (lane == k) mrow[(size_t)k * MW] = bw;
  }
}

// ------------- sparse accumulate: Z1[b][t][o] = sum_{active i, ascending} W1T[i][o] -------------
// One 64-thread block per (b,t,o-chunk-of-128). Grid id = bt*4+oc so the default
// blockIdx%NXCD round-robin gives each XCD a fixed o-chunk -> per-XCD gather
// working set = 2312*512B = 1.18 MB, L2-resident. Ascending-i order per output
// element is identical to previous rounds (bit-identical fp32 sums).
__global__ __launch_bounds__(64) void accum1_k(const unsigned long long* __restrict__ msk,
                                               const float* __restrict__ WT,
                                               float* __restrict__ Z1) {
  __shared__ unsigned short list[MAXA2];
  __shared__ int ntot;
  int id = blockIdx.x;
  int bt = id >> 2, oc = id & 3;
  int lane = threadIdx.x;
  unsigned long long wm = (lane < NIB) ? msk[(size_t)bt * MW + lane] : 0ull;
  int pc = __popcll(wm);
  int pre = pc;
#pragma unroll
  for (int d = 1; d < 64; d <<= 1) {
    int o = __shfl_up(pre, d);
    if (lane >= d) pre += o;
  }
  int base = pre - pc;                  // exclusive prefix
  if (lane == 63) ntot = pre;
  while (wm) {
    int j = __builtin_ctzll(wm);
    if (base < MAXA2) list[base] = (unsigned short)(lane * 64 + j);
    ++base;
    wm &= wm - 1;
  }
  __syncthreads();
  int n = ntot;
  if (n > MAXA2) n = MAXA2;
  const float2* wbase = (const float2*)WT + (size_t)oc * 64 + lane;  // float2 units
  float a0 = 0.f, a1 = 0.f;
#pragma unroll 8
  for (int j = 0; j < n; ++j) {
    float2 v = wbase[(size_t)list[j] * (NHID_ / 2)];
    a0 += v.x;                          // strict ascending-i order per output element
    a1 += v.y;
  }
  ((float2*)(Z1 + (size_t)bt * NHID_))[(size_t)oc * 64 + lane] = make_float2(a0, a1);
}

// ------------- layer-1 scan: truncated-PSP dual IIR (fp64) + refractory (fp32) -------------
// 64-thread blocks, one wave per (b, h-group-of-64). 16-deep register prefetch;
// spikes recorded via per-wave ballot (wave exclusively owns its mask word).
__global__ __launch_bounds__(64) void scan1_k(const float* __restrict__ Z1,
                                              unsigned long long* __restrict__ mask) {
  int lane = threadIdx.x;
  int b = blockIdx.x >> 3, g = blockIdx.x & 7;
  int h = g * 64 + lane;
  const double dp   = exp(-0.1);            // PSP decay per step
  const double Ap   = exp(1.0) / 10.0;      // kernel scale (e/tau) x Ts
  const double D77  = exp(-7.7);            // dp^77
  const float  Dref = (float)exp(-1.0);
  const float  Cref = (float)(-20.0 * exp(1.0));  // -SCALE_REF*THETA*e*Ts/TAU_REF
  double Xc = 0.0, Yc = 0.0, Xd = 0.0, Yd = 0.0;
  float xr = 0.f, yr = 0.f;
  const float* zb = Z1 + (size_t)b * T_ * NHID_ + h;
  unsigned long long* mb = mask + (size_t)b * T_ * 8 + g;
  for (int t0 = 0; t0 < T_; t0 += 16) {
    float z[16], zd[16];
#pragma unroll
    for (int k = 0; k < 16; ++k) {
      int t = t0 + k;
      z[k]  = (t < T_) ? zb[(size_t)t * NHID_] : 0.f;
      zd[k] = (t >= KLEN && t < T_) ? zb[(size_t)(t - KLEN) * NHID_] : 0.f;
    }
#pragma unroll
    for (int k = 0; k < 16; ++k) {
      int t = t0 + k;
      if (t >= T_) break;                 // uniform
      Yc = dp * (Yc + Xc); Xc = dp * Xc + (double)z[k];
      Yd = dp * (Yd + Xd); Xd = dp * Xd + (double)zd[k];
      float p = (float)(Ap * (Yc - D77 * (Yd + 77.0 * Xd)));
      yr = Dref * (yr + xr);
      float u = p + Cref * yr;
      float s = (u >= 10.0f) ? 1.0f : 0.0f;
      xr = Dref * xr + s;
      unsigned long long bw = __ballot(u >= 10.0f);
      if (lane == 0) mb[(size_t)t * 8] = bw;
    }
  }
}

// ------------- layer-2 GEMM via spike bitmask: Z2[b][o][t] = sum_{h set, ascending} W2[o][h] -------------
__global__ __launch_bounds__(256) void z2_k(const unsigned long long* __restrict__ mask,
                                            const float* __restrict__ W2,
                                            float* __restrict__ Z2) {
  int wave = blockIdx.x * 4 + (threadIdx.x >> 6);
  int lane = threadIdx.x & 63;
  if (wave >= B_ * T_) return;
  int b = wave / T_, t = wave - b * T_;
  const unsigned long long* m = mask + (size_t)wave * 8;
  if (lane < NOUT_) {
    const float* wr = W2 + (size_t)lane * NHID_;
    float acc = 0.f;
#pragma unroll
    for (int w = 0; w < 8; ++w) {
      unsigned long long mm = m[w];
      while (mm) {
        int j = __builtin_ctzll(mm);
        mm &= mm - 1;
        acc += wr[w * 64 + j];
      }
    }
    Z2[((size_t)b * NOUT_ + lane) * T_ + t] = acc;
  }
}

// ------------- layer-2 scan -> output spikes (16-deep prefetch) -------------
__global__ __launch_bounds__(64) void scan2_k(const float* __restrict__ Z2,
                                              float* __restrict__ out) {
  int n = blockIdx.x * 64 + threadIdx.x;    // n = b*NOUT + o
  if (n >= B_ * NOUT_) return;
  const double dp   = exp(-0.1);
  const double Ap   = exp(1.0) / 10.0;
  const double D77  = exp(-7.7);
  const float  Dref = (float)exp(-1.0);
  const float  Cref = (float)(-20.0 * exp(1.0));
  double Xc = 0.0, Yc = 0.0, Xd = 0.0, Yd = 0.0;
  float xr = 0.f, yr = 0.f;
  const float* row = Z2 + (size_t)n * T_;
  float* orow = out + (size_t)n * T_;
  for (int t0 = 0; t0 < T_; t0 += 16) {
    float z[16], zd[16];
#pragma unroll
    for (int k = 0; k < 16; ++k) {
      int t = t0 + k;
      z[k]  = (t < T_) ? row[t] : 0.f;
      zd[k] = (t >= KLEN && t < T_) ? row[t - KLEN] : 0.f;
    }
#pragma unroll
    for (int k = 0; k < 16; ++k) {
      int t = t0 + k;
      if (t >= T_) break;                 // uniform
      Yc = dp * (Yc + Xc); Xc = dp * Xc + (double)z[k];
      Yd = dp * (Yd + Xd); Xd = dp * Xd + (double)zd[k];
      float p = (float)(Ap * (Yc - D77 * (Yd + 77.0 * Xd)));
      yr = Dref * (yr + xr);
      float u = p + Cref * yr;
      float s = (u >= 10.0f) ? 1.0f : 0.0f;
      xr = Dref * xr + s;
      orow[t] = s;   // spk / Ts, Ts = 1
    }
  }
}

extern "C" void kernel_launch(void* const* d_in, const int* in_sizes, int n_in,
                              void* d_out, int out_size, void* d_ws, size_t ws_size,
                              hipStream_t stream) {
  const float* X  = (const float*)d_in[0];  // (32, 2312, 350)
  const float* W1 = (const float*)d_in[1];  // (512, 2312)
  const float* W2 = (const float*)d_in[2];  // (10, 512)
  float* out = (float*)d_out;               // (32, 10, 350)

  char* ws = (char*)d_ws;
  size_t off = 0;
  float* W1T = (float*)(ws + off);                 off += (size_t)NIN_ * NHID_ * 4;         // 4.73 MB
  unsigned long long* msk = (unsigned long long*)(ws + off); off += (size_t)B_ * T_ * MW * 8; // 3.58 MB
  float* Z1 = (float*)(ws + off);                  off += (size_t)B_ * T_ * NHID_ * 4;      // 22.9 MB
  unsigned long long* mask = (unsigned long long*)(ws + off); off += (size_t)B_ * T_ * 8 * 8; // 0.72 MB
  float* Z2 = (float*)(ws + off);                  off += (size_t)B_ * NOUT_ * T_ * 4;      // 0.45 MB
  if (off > ws_size) return;  // workspace too small -> fail loudly (no launches)

  w1t_k<<<dim3((NIN_ + 31) / 32, NHID_ / 32), dim3(32, 8), 0, stream>>>(W1, W1T);
  inmask_k<<<(B_ * NIB * NTC + 3) / 4, 256, 0, stream>>>(X, msk);
  accum1_k<<<B_ * T_ * 4, 64, 0, stream>>>(msk, W1T, Z1);
  scan1_k<<<B_ * 8, 64, 0, stream>>>(Z1, mask);
  z2_k<<<(B_ * T_ + 3) / 4, 256, 0, stream>>>(mask, W2, Z2);
  scan2_k<<<(B_ * NOUT_ + 63) / 64, 64, 0, stream>>>(Z2, out);
}

// Round 5
// 398.534 us; speedup vs baseline: 1.0924x; 1.0924x over previous
//
#include <hip/hip_runtime.h>
#include <hip/hip_bf16.h>
#include <math.h>

#define B_    32
#define NIN_  2312
#define NHID_ 512
#define NOUT_ 10
#define T_    350
#define KLEN  77      // truncated SRM alpha kernel length (taps 0..76)
#define MW    40      // u64 words per (b,t) input mask row (37 used, padded)
#define NIB   37      // ceil(NIN/64)
#define NTC   22      // ceil(T/16)
#define MAXA2 320     // max active inputs per (b,t); Binom(2312,0.03) max ~110

// ---------------- W1 transpose: W1[o][i] -> W1T[i][o] ----------------
__global__ __launch_bounds__(256) void w1t_k(const float* __restrict__ W,
                                             float* __restrict__ WT) {
  __shared__ float tile[32][33];
  int i0 = blockIdx.x * 32, o0 = blockIdx.y * 32;
  int tx = threadIdx.x, tyb = threadIdx.y;
#pragma unroll
  for (int s = 0; s < 4; ++s) {
    int ty = tyb + s * 8;
    int o = o0 + ty, i = i0 + tx;
    if (i < NIN_) tile[ty][tx] = W[(size_t)o * NIN_ + i];
  }
  __syncthreads();
#pragma unroll
  for (int s = 0; s < 4; ++s) {
    int ty = tyb + s * 8;
    int i = i0 + ty, o = o0 + tx;
    if (i < NIN_) WT[(size_t)i * NHID_ + o] = tile[tx][ty];
  }
}

// ------------- input bitmask via ballot-transpose: NO atomics, no memset -------------
__global__ __launch_bounds__(256) void inmask_k(const float* __restrict__ X,
                                                unsigned long long* __restrict__ msk) {
  int w = blockIdx.x * 4 + (threadIdx.x >> 6);
  int lane = threadIdx.x & 63;
  if (w >= B_ * NIB * NTC) return;
  int b = w / (NIB * NTC);
  int rem = w - b * (NIB * NTC);
  int iblk = rem / NTC, tc = rem - iblk * NTC;
  int i = iblk * 64 + lane;
  int t0 = tc * 16;
  int nk = (t0 + 16 <= T_) ? 16 : (T_ - t0);      // wave-uniform (depends on tc only)
  bool valid = (i < NIN_);
  const float2* rp = (const float2*)(X + ((size_t)b * NIN_ + (valid ? i : 0)) * T_ + t0);
  float2 v[8];
#pragma unroll
  for (int q = 0; q < 8; ++q) v[q] = make_float2(0.f, 0.f);
  if (valid) {
    int nw = nk >> 1;
    for (int q = 0; q < nw; ++q) v[q] = rp[q];
  }
  unsigned long long* mrow = msk + ((size_t)b * T_ + t0) * MW + iblk;
#pragma unroll
  for (int k = 0; k < 16; ++k) {
    if (k >= nk) break;                            // wave-uniform exit
    float xv = (k & 1) ? v[k >> 1].y : v[k >> 1].x;
    unsigned long long bw = __ballot(xv != 0.0f);
    if (lane == k) mrow[(size_t)k * MW] = bw;
  }
}

// ------------- sparse accumulate: Z1[b][t][o] = sum_{active i, ascending} W1T[i][o] -------------
// One 64-thread block per (b,t,o-half-of-256). float4 gathers: 1 KB per wave-inst
// (2 insts per 2 KB row vs 4 with float2) -> halves the vector-mem instruction
// count, which round-3/4 evidence says is the limiter. Each output column still
// sums in strict ascending-i serial order -> bit-identical to prior rounds.
__global__ __launch_bounds__(64) void accum1_k(const unsigned long long* __restrict__ msk,
                                               const float* __restrict__ WT,
                                               float* __restrict__ Z1) {
  __shared__ unsigned short list[MAXA2];
  int id = blockIdx.x;
  int bt = id >> 1, oc = id & 1;
  int lane = threadIdx.x;
  unsigned long long wm = (lane < NIB) ? msk[(size_t)bt * MW + lane] : 0ull;
  int pc = __popcll(wm);
  int pre = pc;
#pragma unroll
  for (int d = 1; d < 64; d <<= 1) {
    int o = __shfl_up(pre, d);
    if (lane >= d) pre += o;
  }
  int base = pre - pc;                  // exclusive prefix
  int n = __shfl(pre, 63);              // total actives (single wave -> shfl, no LDS flag)
  while (wm) {
    int j = __builtin_ctzll(wm);
    if (base < MAXA2) list[base] = (unsigned short)(lane * 64 + j);
    ++base;
    wm &= wm - 1;
  }
  __syncthreads();                      // lgkmcnt drain for LDS list (single wave)
  if (n > MAXA2) n = MAXA2;
  const float4* wbase = (const float4*)WT + (size_t)oc * 64 + lane;  // float4 units
  float4 acc = make_float4(0.f, 0.f, 0.f, 0.f);
#pragma unroll 8
  for (int j = 0; j < n; ++j) {
    float4 v = wbase[(size_t)list[j] * (NHID_ / 4)];
    acc.x += v.x;                       // strict ascending-i order per output column
    acc.y += v.y;
    acc.z += v.z;
    acc.w += v.w;
  }
  ((float4*)(Z1 + (size_t)bt * NHID_))[(size_t)oc * 64 + lane] = acc;
}

// ------------- layer-1 scan: truncated-PSP dual IIR (fp64) + refractory (fp32) -------------
__global__ __launch_bounds__(64) void scan1_k(const float* __restrict__ Z1,
                                              unsigned long long* __restrict__ mask) {
  int lane = threadIdx.x;
  int b = blockIdx.x >> 3, g = blockIdx.x & 7;
  int h = g * 64 + lane;
  const double dp   = exp(-0.1);            // PSP decay per step
  const double Ap   = exp(1.0) / 10.0;      // kernel scale (e/tau) x Ts
  const double D77  = exp(-7.7);            // dp^77
  const float  Dref = (float)exp(-1.0);
  const float  Cref = (float)(-20.0 * exp(1.0));  // -SCALE_REF*THETA*e*Ts/TAU_REF
  double Xc = 0.0, Yc = 0.0, Xd = 0.0, Yd = 0.0;
  float xr = 0.f, yr = 0.f;
  const float* zb = Z1 + (size_t)b * T_ * NHID_ + h;
  unsigned long long* mb = mask + (size_t)b * T_ * 8 + g;
  for (int t0 = 0; t0 < T_; t0 += 16) {
    float z[16], zd[16];
#pragma unroll
    for (int k = 0; k < 16; ++k) {
      int t = t0 + k;
      z[k]  = (t < T_) ? zb[(size_t)t * NHID_] : 0.f;
      zd[k] = (t >= KLEN && t < T_) ? zb[(size_t)(t - KLEN) * NHID_] : 0.f;
    }
#pragma unroll
    for (int k = 0; k < 16; ++k) {
      int t = t0 + k;
      if (t >= T_) break;                 // uniform
      Yc = dp * (Yc + Xc); Xc = dp * Xc + (double)z[k];
      Yd = dp * (Yd + Xd); Xd = dp * Xd + (double)zd[k];
      float p = (float)(Ap * (Yc - D77 * (Yd + 77.0 * Xd)));
      yr = Dref * (yr + xr);
      float u = p + Cref * yr;
      float s = (u >= 10.0f) ? 1.0f : 0.0f;
      xr = Dref * xr + s;
      unsigned long long bw = __ballot(u >= 10.0f);
      if (lane == 0) mb[(size_t)t * 8] = bw;
    }
  }
}

// ------------- layer-2 GEMM via spike bitmask: Z2[b][o][t] = sum_{h set, ascending} W2[o][h] -------------
__global__ __launch_bounds__(256) void z2_k(const unsigned long long* __restrict__ mask,
                                            const float* __restrict__ W2,
                                            float* __restrict__ Z2) {
  int wave = blockIdx.x * 4 + (threadIdx.x >> 6);
  int lane = threadIdx.x & 63;
  if (wave >= B_ * T_) return;
  int b = wave / T_, t = wave - b * T_;
  const unsigned long long* m = mask + (size_t)wave * 8;
  if (lane < NOUT_) {
    const float* wr = W2 + (size_t)lane * NHID_;
    float acc = 0.f;
#pragma unroll
    for (int w = 0; w < 8; ++w) {
      unsigned long long mm = m[w];
      while (mm) {
        int j = __builtin_ctzll(mm);
        mm &= mm - 1;
        acc += wr[w * 64 + j];
      }
    }
    Z2[((size_t)b * NOUT_ + lane) * T_ + t] = acc;
  }
}

// ------------- layer-2 scan -> output spikes (16-deep prefetch) -------------
__global__ __launch_bounds__(64) void scan2_k(const float* __restrict__ Z2,
                                              float* __restrict__ out) {
  int n = blockIdx.x * 64 + threadIdx.x;    // n = b*NOUT + o
  if (n >= B_ * NOUT_) return;
  const double dp   = exp(-0.1);
  const double Ap   = exp(1.0) / 10.0;
  const double D77  = exp(-7.7);
  const float  Dref = (float)exp(-1.0);
  const float  Cref = (float)(-20.0 * exp(1.0));
  double Xc = 0.0, Yc = 0.0, Xd = 0.0, Yd = 0.0;
  float xr = 0.f, yr = 0.f;
  const float* row = Z2 + (size_t)n * T_;
  float* orow = out + (size_t)n * T_;
  for (int t0 = 0; t0 < T_; t0 += 16) {
    float z[16], zd[16];
#pragma unroll
    for (int k = 0; k < 16; ++k) {
      int t = t0 + k;
      z[k]  = (t < T_) ? row[t] : 0.f;
      zd[k] = (t >= KLEN && t < T_) ? row[t - KLEN] : 0.f;
    }
#pragma unroll
    for (int k = 0; k < 16; ++k) {
      int t = t0 + k;
      if (t >= T_) break;                 // uniform
      Yc = dp * (Yc + Xc); Xc = dp * Xc + (double)z[k];
      Yd = dp * (Yd + Xd); Xd = dp * Xd + (double)zd[k];
      float p = (float)(Ap * (Yc - D77 * (Yd + 77.0 * Xd)));
      yr = Dref * (yr + xr);
      float u = p + Cref * yr;
      float s = (u >= 10.0f) ? 1.0f : 0.0f;
      xr = Dref * xr + s;
      orow[t] = s;   // spk / Ts, Ts = 1
    }
  }
}

extern "C" void kernel_launch(void* const* d_in, const int* in_sizes, int n_in,
                              void* d_out, int out_size, void* d_ws, size_t ws_size,
                              hipStream_t stream) {
  const float* X  = (const float*)d_in[0];  // (32, 2312, 350)
  const float* W1 = (const float*)d_in[1];  // (512, 2312)
  const float* W2 = (const float*)d_in[2];  // (10, 512)
  float* out = (float*)d_out;               // (32, 10, 350)

  char* ws = (char*)d_ws;
  size_t off = 0;
  float* W1T = (float*)(ws + off);                 off += (size_t)NIN_ * NHID_ * 4;         // 4.73 MB
  unsigned long long* msk = (unsigned long long*)(ws + off); off += (size_t)B_ * T_ * MW * 8; // 3.58 MB
  float* Z1 = (float*)(ws + off);                  off += (size_t)B_ * T_ * NHID_ * 4;      // 22.9 MB
  unsigned long long* mask = (unsigned long long*)(ws + off); off += (size_t)B_ * T_ * 8 * 8; // 0.72 MB
  float* Z2 = (float*)(ws + off);                  off += (size_t)B_ * NOUT_ * T_ * 4;      // 0.45 MB
  if (off > ws_size) return;  // workspace too small -> fail loudly (no launches)

  w1t_k<<<dim3((NIN_ + 31) / 32, NHID_ / 32), dim3(32, 8), 0, stream>>>(W1, W1T);
  inmask_k<<<(B_ * NIB * NTC + 3) / 4, 256, 0, stream>>>(X, msk);
  accum1_k<<<B_ * T_ * 2, 64, 0, stream>>>(msk, W1T, Z1);
  scan1_k<<<B_ * 8, 64, 0, stream>>>(Z1, mask);
  z2_k<<<(B_ * T_ + 3) / 4, 256, 0, stream>>>(mask, W2, Z2);
  scan2_k<<<(B_ * NOUT_ + 63) / 64, 64, 0, stream>>>(Z2, out);
}

// Round 6
// 396.218 us; speedup vs baseline: 1.0987x; 1.0058x over previous
//
#include <hip/hip_runtime.h>
#include <hip/hip_bf16.h>
#include <math.h>

#define B_    32
#define NIN_  2312
#define NHID_ 512
#define NOUT_ 10
#define T_    350
#define KLEN  77      // truncated SRM alpha kernel length (taps 0..76)
#define MW    40      // u64 words per (b,t) input mask row (37 used, padded)
#define NIB   37      // ceil(NIN/64)
#define NTC   22      // ceil(T/16)
#define MAXA2 320     // max active inputs per (b,t); Binom(2312,0.03) max ~110

// ---------------- W1 transpose: W1[o][i] -> W1T[i][o] ----------------
__global__ __launch_bounds__(256) void w1t_k(const float* __restrict__ W,
                                             float* __restrict__ WT) {
  __shared__ float tile[32][33];
  int i0 = blockIdx.x * 32, o0 = blockIdx.y * 32;
  int tx = threadIdx.x, tyb = threadIdx.y;
#pragma unroll
  for (int s = 0; s < 4; ++s) {
    int ty = tyb + s * 8;
    int o = o0 + ty, i = i0 + tx;
    if (i < NIN_) tile[ty][tx] = W[(size_t)o * NIN_ + i];
  }
  __syncthreads();
#pragma unroll
  for (int s = 0; s < 4; ++s) {
    int ty = tyb + s * 8;
    int i = i0 + ty, o = o0 + tx;
    if (i < NIN_) WT[(size_t)i * NHID_ + o] = tile[tx][ty];
  }
}

// ------------- input bitmask via ballot-transpose: NO atomics, no memset -------------
// wave owns (b, 64-i block, 16-t chunk); lane = i. ALL v[] indices are
// compile-time (fully unrolled, per-element predication) so SROA keeps the
// array in VGPRs — a runtime-bound load loop here gets demoted to LDS
// (AMDGPUPromoteAlloca) and was a 32-way bank-conflict disaster in round 5.
__global__ __launch_bounds__(256) void inmask_k(const float* __restrict__ X,
                                                unsigned long long* __restrict__ msk) {
  int w = blockIdx.x * 4 + (threadIdx.x >> 6);
  int lane = threadIdx.x & 63;
  if (w >= B_ * NIB * NTC) return;
  int b = w / (NIB * NTC);
  int rem = w - b * (NIB * NTC);
  int iblk = rem / NTC, tc = rem - iblk * NTC;
  int i = iblk * 64 + lane;
  int t0 = tc * 16;
  int nk = (t0 + 16 <= T_) ? 16 : (T_ - t0);      // wave-uniform (depends on tc only)
  int nw = nk >> 1;
  bool valid = (i < NIN_);
  const float2* rp = (const float2*)(X + ((size_t)b * NIN_ + (valid ? i : 0)) * T_ + t0);
  float2 v[8];
#pragma unroll
  for (int q = 0; q < 8; ++q)
    v[q] = (valid && q < nw) ? rp[q] : make_float2(0.f, 0.f);
  unsigned long long* mrow = msk + ((size_t)b * T_ + t0) * MW + iblk;
#pragma unroll
  for (int k = 0; k < 16; ++k) {
    if (k >= nk) break;                            // wave-uniform exit
    float xv = (k & 1) ? v[k >> 1].y : v[k >> 1].x;
    unsigned long long bw = __ballot(xv != 0.0f);
    if (lane == k) mrow[(size_t)k * MW] = bw;
  }
}

// ------------- sparse accumulate: Z1[b][t][o] = sum_{active i, ascending} W1T[i][o] -------------
// One 64-thread block per (b,t,o-half-of-256). float4 gathers (1 KB/wave-inst).
// Each output column sums in strict ascending-i serial order -> bit-identical
// to prior rounds.
__global__ __launch_bounds__(64) void accum1_k(const unsigned long long* __restrict__ msk,
                                               const float* __restrict__ WT,
                                               float* __restrict__ Z1) {
  __shared__ unsigned short list[MAXA2];
  int id = blockIdx.x;
  int bt = id >> 1, oc = id & 1;
  int lane = threadIdx.x;
  unsigned long long wm = (lane < NIB) ? msk[(size_t)bt * MW + lane] : 0ull;
  int pc = __popcll(wm);
  int pre = pc;
#pragma unroll
  for (int d = 1; d < 64; d <<= 1) {
    int o = __shfl_up(pre, d);
    if (lane >= d) pre += o;
  }
  int base = pre - pc;                  // exclusive prefix
  int n = __shfl(pre, 63);              // total actives
  while (wm) {
    int j = __builtin_ctzll(wm);
    if (base < MAXA2) list[base] = (unsigned short)(lane * 64 + j);
    ++base;
    wm &= wm - 1;
  }
  __syncthreads();
  if (n > MAXA2) n = MAXA2;
  const float4* wbase = (const float4*)WT + (size_t)oc * 64 + lane;  // float4 units
  float4 acc = make_float4(0.f, 0.f, 0.f, 0.f);
#pragma unroll 8
  for (int j = 0; j < n; ++j) {
    float4 v = wbase[(size_t)list[j] * (NHID_ / 4)];
    acc.x += v.x;                       // strict ascending-i order per output column
    acc.y += v.y;
    acc.z += v.z;
    acc.w += v.w;
  }
  ((float4*)(Z1 + (size_t)bt * NHID_))[(size_t)oc * 64 + lane] = acc;
}

// ------------- layer-1 scan: truncated-PSP dual IIR (fp64) + refractory (fp32) -------------
__global__ __launch_bounds__(64) void scan1_k(const float* __restrict__ Z1,
                                              unsigned long long* __restrict__ mask) {
  int lane = threadIdx.x;
  int b = blockIdx.x >> 3, g = blockIdx.x & 7;
  int h = g * 64 + lane;
  const double dp   = exp(-0.1);            // PSP decay per step
  const double Ap   = exp(1.0) / 10.0;      // kernel scale (e/tau) x Ts
  const double D77  = exp(-7.7);            // dp^77
  const float  Dref = (float)exp(-1.0);
  const float  Cref = (float)(-20.0 * exp(1.0));  // -SCALE_REF*THETA*e*Ts/TAU_REF
  double Xc = 0.0, Yc = 0.0, Xd = 0.0, Yd = 0.0;
  float xr = 0.f, yr = 0.f;
  const float* zb = Z1 + (size_t)b * T_ * NHID_ + h;
  unsigned long long* mb = mask + (size_t)b * T_ * 8 + g;
  for (int t0 = 0; t0 < T_; t0 += 16) {
    float z[16], zd[16];
#pragma unroll
    for (int k = 0; k < 16; ++k) {
      int t = t0 + k;
      z[k]  = (t < T_) ? zb[(size_t)t * NHID_] : 0.f;
      zd[k] = (t >= KLEN && t < T_) ? zb[(size_t)(t - KLEN) * NHID_] : 0.f;
    }
#pragma unroll
    for (int k = 0; k < 16; ++k) {
      int t = t0 + k;
      if (t >= T_) break;                 // uniform
      Yc = dp * (Yc + Xc); Xc = dp * Xc + (double)z[k];
      Yd = dp * (Yd + Xd); Xd = dp * Xd + (double)zd[k];
      float p = (float)(Ap * (Yc - D77 * (Yd + 77.0 * Xd)));
      yr = Dref * (yr + xr);
      float u = p + Cref * yr;
      float s = (u >= 10.0f) ? 1.0f : 0.0f;
      xr = Dref * xr + s;
      unsigned long long bw = __ballot(u >= 10.0f);
      if (lane == 0) mb[(size_t)t * 8] = bw;
    }
  }
}

// ------------- layer-2 GEMM via spike bitmask: Z2[b][o][t] = sum_{h set, ascending} W2[o][h] -------------
__global__ __launch_bounds__(256) void z2_k(const unsigned long long* __restrict__ mask,
                                            const float* __restrict__ W2,
                                            float* __restrict__ Z2) {
  int wave = blockIdx.x * 4 + (threadIdx.x >> 6);
  int lane = threadIdx.x & 63;
  if (wave >= B_ * T_) return;
  int b = wave / T_, t = wave - b * T_;
  const unsigned long long* m = mask + (size_t)wave * 8;
  if (lane < NOUT_) {
    const float* wr = W2 + (size_t)lane * NHID_;
    float acc = 0.f;
#pragma unroll
    for (int w = 0; w < 8; ++w) {
      unsigned long long mm = m[w];
      while (mm) {
        int j = __builtin_ctzll(mm);
        mm &= mm - 1;
        acc += wr[w * 64 + j];
      }
    }
    Z2[((size_t)b * NOUT_ + lane) * T_ + t] = acc;
  }
}

// ------------- layer-2 scan -> output spikes (16-deep prefetch) -------------
__global__ __launch_bounds__(64) void scan2_k(const float* __restrict__ Z2,
                                              float* __restrict__ out) {
  int n = blockIdx.x * 64 + threadIdx.x;    // n = b*NOUT + o
  if (n >= B_ * NOUT_) return;
  const double dp   = exp(-0.1);
  const double Ap   = exp(1.0) / 10.0;
  const double D77  = exp(-7.7);
  const float  Dref = (float)exp(-1.0);
  const float  Cref = (float)(-20.0 * exp(1.0));
  double Xc = 0.0, Yc = 0.0, Xd = 0.0, Yd = 0.0;
  float xr = 0.f, yr = 0.f;
  const float* row = Z2 + (size_t)n * T_;
  float* orow = out + (size_t)n * T_;
  for (int t0 = 0; t0 < T_; t0 += 16) {
    float z[16], zd[16];
#pragma unroll
    for (int k = 0; k < 16; ++k) {
      int t = t0 + k;
      z[k]  = (t < T_) ? row[t] : 0.f;
      zd[k] = (t >= KLEN && t < T_) ? row[t - KLEN] : 0.f;
    }
#pragma unroll
    for (int k = 0; k < 16; ++k) {
      int t = t0 + k;
      if (t >= T_) break;                 // uniform
      Yc = dp * (Yc + Xc); Xc = dp * Xc + (double)z[k];
      Yd = dp * (Yd + Xd); Xd = dp * Xd + (double)zd[k];
      float p = (float)(Ap * (Yc - D77 * (Yd + 77.0 * Xd)));
      yr = Dref * (yr + xr);
      float u = p + Cref * yr;
      float s = (u >= 10.0f) ? 1.0f : 0.0f;
      xr = Dref * xr + s;
      orow[t] = s;   // spk / Ts, Ts = 1
    }
  }
}

extern "C" void kernel_launch(void* const* d_in, const int* in_sizes, int n_in,
                              void* d_out, int out_size, void* d_ws, size_t ws_size,
                              hipStream_t stream) {
  const float* X  = (const float*)d_in[0];  // (32, 2312, 350)
  const float* W1 = (const float*)d_in[1];  // (512, 2312)
  const float* W2 = (const float*)d_in[2];  // (10, 512)
  float* out = (float*)d_out;               // (32, 10, 350)

  char* ws = (char*)d_ws;
  size_t off = 0;
  float* W1T = (float*)(ws + off);                 off += (size_t)NIN_ * NHID_ * 4;         // 4.73 MB
  unsigned long long* msk = (unsigned long long*)(ws + off); off += (size_t)B_ * T_ * MW * 8; // 3.58 MB
  float* Z1 = (float*)(ws + off);                  off += (size_t)B_ * T_ * NHID_ * 4;      // 22.9 MB
  unsigned long long* mask = (unsigned long long*)(ws + off); off += (size_t)B_ * T_ * 8 * 8; // 0.72 MB
  float* Z2 = (float*)(ws + off);                  off += (size_t)B_ * NOUT_ * T_ * 4;      // 0.45 MB
  if (off > ws_size) return;  // workspace too small -> fail loudly (no launches)

  w1t_k<<<dim3((NIN_ + 31) / 32, NHID_ / 32), dim3(32, 8), 0, stream>>>(W1, W1T);
  inmask_k<<<(B_ * NIB * NTC + 3) / 4, 256, 0, stream>>>(X, msk);
  accum1_k<<<B_ * T_ * 2, 64, 0, stream>>>(msk, W1T, Z1);
  scan1_k<<<B_ * 8, 64, 0, stream>>>(Z1, mask);
  z2_k<<<(B_ * T_ + 3) / 4, 256, 0, stream>>>(mask, W2, Z2);
  scan2_k<<<(B_ * NOUT_ + 63) / 64, 64, 0, stream>>>(Z2, out);
}